// Round 9
// baseline (376.439 us; speedup 1.0000x reference)
//
#include <hip/hip_runtime.h>
#include <hip/hip_cooperative_groups.h>
#include <hip/hip_bf16.h>
#include <hip/hip_fp16.h>
#include <math.h>

namespace cg = cooperative_groups;

#define D 128
#define BIN_SHIFT 8      // 256 rows per coarse bin
#define BIN_ROWS 256
#define NB_MAX 512       // >= nbins (391 for 100k nodes)
#define CPAD 16          // ints; one 64B line per coarse cursor
#define AW 2048          // edges per stage-A window (256 thr x 8)

typedef _Float16 half8 __attribute__((ext_vector_type(8)));
typedef float floatx4 __attribute__((ext_vector_type(4)));
typedef float floatx2 __attribute__((ext_vector_type(2)));

// ===================== device bodies (shared by mega + fallback) ==========

__device__ __forceinline__ void wt_body(const float* __restrict__ W,
                                        unsigned short* __restrict__ wt,
                                        int* __restrict__ cbin,
                                        int bid, int nblk) {
    const int t = threadIdx.x;
    for (int i = bid * 256 + t; i < D * D; i += nblk * 256) {
        const int n = i >> 7, k = i & 127;
        wt[i] = __half_as_ushort(__float2half_rn(W[k * D + n]));
    }
    for (int i = bid * 256 + t; i < NB_MAX; i += nblk * 256) cbin[i] = 0;
}

__device__ __forceinline__ void gemm_body(const float* __restrict__ x,
                                          const unsigned short* __restrict__ wt,
                                          unsigned short* __restrict__ support2,
                                          int n_nodes, int tile) {
    const int wave = threadIdx.x >> 6;
    const int lane = threadIdx.x & 63;
    const int q = lane >> 4;
    const int n16 = lane & 15;
    const int row_base = tile * 128 + wave * 32;
    if (row_base >= n_nodes) return;  // device fn return ok (no syncs below)

    const half8* wt8 = (const half8*)wt;

    floatx4 acc[2][8];
#pragma unroll
    for (int mt = 0; mt < 2; ++mt)
#pragma unroll
        for (int nt = 0; nt < 8; ++nt) acc[mt][nt] = (floatx4){0.f, 0.f, 0.f, 0.f};

#pragma unroll
    for (int kc = 0; kc < 4; ++kc) {
        half8 b[8];
#pragma unroll
        for (int nt = 0; nt < 8; ++nt)
            b[nt] = wt8[(nt * 16 + n16) * 16 + kc * 4 + q];
#pragma unroll
        for (int mt = 0; mt < 2; ++mt) {
            const float* xp = x + (size_t)(row_base + mt * 16 + n16) * D
                                + kc * 32 + q * 8;
            const float4 f0 = *(const float4*)xp;
            const float4 f1 = *(const float4*)(xp + 4);
            half8 a;
            a[0] = (_Float16)f0.x; a[1] = (_Float16)f0.y;
            a[2] = (_Float16)f0.z; a[3] = (_Float16)f0.w;
            a[4] = (_Float16)f1.x; a[5] = (_Float16)f1.y;
            a[6] = (_Float16)f1.z; a[7] = (_Float16)f1.w;
#pragma unroll
            for (int nt = 0; nt < 8; ++nt)
                acc[mt][nt] = __builtin_amdgcn_mfma_f32_16x16x32_f16(
                    a, b[nt], acc[mt][nt], 0, 0, 0);
        }
    }

#pragma unroll
    for (int mt = 0; mt < 2; ++mt) {
        const int r0 = row_base + mt * 16 + q * 4;
#pragma unroll
        for (int nt = 0; nt < 8; ++nt) {
            const int col = nt * 16 + n16;
#pragma unroll
            for (int i = 0; i < 4; ++i)
                support2[(size_t)(r0 + i) * D + col] =
                    __half_as_ushort(__float2half_rn(acc[mt][nt][i]));
        }
    }
}

__device__ __forceinline__ void chist_body(const int* __restrict__ erow,
                                           int* __restrict__ cbin,
                                           int n_edges, int bid, int nblk,
                                           int* h) {
    const int t = threadIdx.x;
    h[t] = 0;
    h[t + 256] = 0;
    __syncthreads();
    const int stride = nblk * 256 * 4;
    const int nv = n_edges & ~3;
    for (int i = (bid * 256 + t) * 4; i + 3 < n_edges; i += stride) {
        const int4 r = *(const int4*)(erow + i);
        atomicAdd(&h[r.x >> BIN_SHIFT], 1);
        atomicAdd(&h[r.y >> BIN_SHIFT], 1);
        atomicAdd(&h[r.z >> BIN_SHIFT], 1);
        atomicAdd(&h[r.w >> BIN_SHIFT], 1);
    }
    if (bid == 0) {  // scalar tail (none for 1.6M, kept for safety)
        for (int i = nv + t; i < n_edges; i += 256)
            atomicAdd(&h[erow[i] >> BIN_SHIFT], 1);
    }
    __syncthreads();
    if (h[t] > 0) atomicAdd(&cbin[t], h[t]);
    if (h[t + 256] > 0) atomicAdd(&cbin[t + 256], h[t + 256]);
}

// block 0 only; 256 threads scan up to 512 bin totals (2 per thread)
__device__ __forceinline__ void cscan_body(const int* __restrict__ cbin,
                                           int* __restrict__ cbase,
                                           int* __restrict__ ccur,
                                           int* __restrict__ offsets,
                                           int nbins, int n_nodes, int n_edges,
                                           int* sm) {
    const int t = threadIdx.x;
    const int v0 = (2 * t < nbins) ? cbin[2 * t] : 0;
    const int v1 = (2 * t + 1 < nbins) ? cbin[2 * t + 1] : 0;
    const int s2 = v0 + v1;
    sm[t] = s2;
    __syncthreads();
    for (int off = 1; off < 256; off <<= 1) {
        int tv = (t >= off) ? sm[t - off] : 0;
        __syncthreads();
        sm[t] += tv;
        __syncthreads();
    }
    const int ex = sm[t] - s2;
    if (2 * t < nbins)     { cbase[2 * t] = ex;          ccur[(2 * t) * CPAD] = ex; }
    if (2 * t + 1 < nbins) { cbase[2 * t + 1] = ex + v0; ccur[(2 * t + 1) * CPAD] = ex + v0; }
    if (t == 0) { cbase[nbins] = n_edges; offsets[n_nodes] = n_edges; }
}

// stage A: one 2048-edge window -> staged counting sort into coarse bins
__device__ __forceinline__ void binA_body(
        const int* __restrict__ erow, const int* __restrict__ ecol,
        const float* __restrict__ eval, int* __restrict__ ccur,
        uint2* __restrict__ tmp8, int n_edges, int nbins, int w,
        int* hist, int* lstart, int* gbase, int* sm, uint2* recs) {
    const int t = threadIdx.x;
    const int w0 = w * AW;
    const int wend = min(w0 + AW, n_edges);
    const int wcnt = wend - w0;

    hist[t] = 0;
    hist[t + 256] = 0;
    __syncthreads();

    for (int i = w0 + t; i < wend; i += 256)
        atomicAdd(&hist[erow[i] >> BIN_SHIFT], 1);
    __syncthreads();

    // exclusive scan over 512 counters (2 per thread)
    const int c0 = hist[2 * t], c1 = hist[2 * t + 1];
    const int s2 = c0 + c1;
    sm[t] = s2;
    __syncthreads();
    for (int off = 1; off < 256; off <<= 1) {
        int tv = (t >= off) ? sm[t - off] : 0;
        __syncthreads();
        sm[t] += tv;
        __syncthreads();
    }
    const int ex = sm[t] - s2;
    lstart[2 * t] = ex;
    lstart[2 * t + 1] = ex + c0;

    // reserve contiguous global ranges (one atomic per used bin)
    {
        int gb0 = 0, gb1 = 0;
        if (2 * t < nbins && c0 > 0)     gb0 = atomicAdd(&ccur[(2 * t) * CPAD], c0);
        if (2 * t + 1 < nbins && c1 > 0) gb1 = atomicAdd(&ccur[(2 * t + 1) * CPAD], c1);
        gbase[2 * t] = gb0;
        gbase[2 * t + 1] = gb1;
    }
    __syncthreads();
    hist[2 * t] = lstart[2 * t];
    hist[2 * t + 1] = lstart[2 * t + 1];
    __syncthreads();

    // local placement into LDS
    for (int i = w0 + t; i < wend; i += 256) {
        const int r = erow[i];
        const int c = ecol[i];
        const unsigned short vh = __half_as_ushort(__float2half_rn(eval[i]));
        const int b = r >> BIN_SHIFT;
        const int p = atomicAdd(&hist[b], 1);
        recs[p] = make_uint2(((unsigned)r << 15) | vh, (unsigned)c);
    }
    __syncthreads();

    // ordered (coalesced-run) write-out
    for (int s = t; s < wcnt; s += 256) {
        const uint2 rec = recs[s];
        const int b = (int)(rec.x >> 15) >> BIN_SHIFT;
        tmp8[gbase[b] + (s - lstart[b])] = rec;
    }
    __syncthreads();  // safe LDS reuse for next window
}

// stage B: one 256-row bin -> per-row offsets + CSR placement
__device__ __forceinline__ void binB_body(
        const uint2* __restrict__ tmp8, const int* __restrict__ cbase,
        int* __restrict__ offsets, unsigned int* __restrict__ rec4,
        int n_nodes, int bin, int* cnt, int* sm) {
    const int r0 = bin << BIN_SHIFT;
    const int t = threadIdx.x;
    cnt[t] = 0;
    __syncthreads();

    const int beg = cbase[bin];
    const int end = cbase[bin + 1];

    for (int i = beg + t; i < end; i += 256)
        atomicAdd(&cnt[(int)(tmp8[i].x >> 15) - r0], 1);
    __syncthreads();

    const int v = cnt[t];
    sm[t] = v;
    __syncthreads();
    for (int off = 1; off < 256; off <<= 1) {
        int tv = (t >= off) ? sm[t - off] : 0;
        __syncthreads();
        sm[t] += tv;
        __syncthreads();
    }
    const int mypos = beg + sm[t] - v;

    const int row = r0 + t;
    if (row < n_nodes) offsets[row] = mypos;
    __syncthreads();
    cnt[t] = mypos;
    __syncthreads();

    for (int i = beg + t; i < end; i += 256) {
        const uint2 p = tmp8[i];
        const int pos = atomicAdd(&cnt[(int)(p.x >> 15) - r0], 1);
        rec4[pos] = (p.y << 15) | (p.x & 0x7FFFu);
    }
    __syncthreads();  // safe LDS reuse for next bin
}

// ===================== cooperative mega-kernel ============================
__global__ __launch_bounds__(256) void gcn_mega_kernel(
        const float* __restrict__ x, const float* __restrict__ W,
        unsigned short* __restrict__ wt, unsigned short* __restrict__ support2,
        const int* __restrict__ erow, const int* __restrict__ ecol,
        const float* __restrict__ eval,
        int* __restrict__ cbin, int* __restrict__ cbase, int* __restrict__ ccur,
        int* __restrict__ offsets, uint2* __restrict__ tmp8,
        unsigned int* __restrict__ rec4,
        int n_nodes, int n_edges, int nbins) {
    __shared__ uint2 recs[AW];     // 16 KB
    __shared__ int smA[NB_MAX];    // 2 KB
    __shared__ int smB[NB_MAX];    // 2 KB
    __shared__ int smC[NB_MAX];    // 2 KB
    __shared__ int smD[256];       // 1 KB
    cg::grid_group grid = cg::this_grid();
    const int bid = blockIdx.x, nblk = gridDim.x;

    // P0: wt transpose + zero cbin
    wt_body(W, wt, cbin, bid, nblk);
    grid.sync();

    // P1: gemm tiles + coarse histogram (independent; both read-only inputs)
    for (int tile = bid; tile * 128 < n_nodes; tile += nblk)
        gemm_body(x, wt, support2, n_nodes, tile);
    chist_body(erow, cbin, n_edges, bid, nblk, smA);
    grid.sync();

    // P2: scan of coarse-bin totals (block 0)
    if (bid == 0)
        cscan_body(cbin, cbase, ccur, offsets, nbins, n_nodes, n_edges, smD);
    grid.sync();

    // P3: stage-A binning
    for (int w = bid; w * AW < n_edges; w += nblk)
        binA_body(erow, ecol, eval, ccur, tmp8, n_edges, nbins, w,
                  smA, smB, smC, smD, recs);
    grid.sync();

    // P4: stage-B CSR build
    for (int b = bid; b < nbins; b += nblk)
        binB_body(tmp8, cbase, offsets, rec4, n_nodes, b, smA, smB);
}

// ===================== fallback wrappers (7-launch path) ==================
__global__ __launch_bounds__(256) void gcn_wt_kernel(
        const float* __restrict__ W, unsigned short* __restrict__ wt,
        int* __restrict__ cbin) {
    wt_body(W, wt, cbin, blockIdx.x, gridDim.x);
}
__global__ __launch_bounds__(256) void gcn_gemm_kernel(
        const float* __restrict__ x, const unsigned short* __restrict__ wt,
        unsigned short* __restrict__ support2, int n_nodes) {
    for (int tile = blockIdx.x; tile * 128 < n_nodes; tile += gridDim.x)
        gemm_body(x, wt, support2, n_nodes, tile);
}
__global__ __launch_bounds__(256) void gcn_chist_kernel(
        const int* __restrict__ erow, int* __restrict__ cbin, int n_edges) {
    __shared__ int smA[NB_MAX];
    chist_body(erow, cbin, n_edges, blockIdx.x, gridDim.x, smA);
}
__global__ __launch_bounds__(256) void gcn_cscan_kernel(
        const int* __restrict__ cbin, int* __restrict__ cbase,
        int* __restrict__ ccur, int* __restrict__ offsets,
        int nbins, int n_nodes, int n_edges) {
    __shared__ int smD[256];
    if (blockIdx.x == 0)
        cscan_body(cbin, cbase, ccur, offsets, nbins, n_nodes, n_edges, smD);
}
__global__ __launch_bounds__(256) void gcn_binA_kernel(
        const int* __restrict__ erow, const int* __restrict__ ecol,
        const float* __restrict__ eval, int* __restrict__ ccur,
        uint2* __restrict__ tmp8, int n_edges, int nbins) {
    __shared__ uint2 recs[AW];
    __shared__ int smA[NB_MAX];
    __shared__ int smB[NB_MAX];
    __shared__ int smC[NB_MAX];
    __shared__ int smD[256];
    for (int w = blockIdx.x; w * AW < n_edges; w += gridDim.x)
        binA_body(erow, ecol, eval, ccur, tmp8, n_edges, nbins, w,
                  smA, smB, smC, smD, recs);
}
__global__ __launch_bounds__(256) void gcn_binB_kernel(
        const uint2* __restrict__ tmp8, const int* __restrict__ cbase,
        int* __restrict__ offsets, unsigned int* __restrict__ rec4,
        int n_nodes, int nbins) {
    __shared__ int smA[NB_MAX];
    __shared__ int smB[NB_MAX];
    for (int b = blockIdx.x; b < nbins; b += gridDim.x)
        binB_body(tmp8, cbase, offsets, rec4, n_nodes, b, smA, smB);
}

// ---------------- per-node reduction + fused tanh (round-5 proven) --------
__global__ __launch_bounds__(256) void gcn_gather_kernel(
        const unsigned int* __restrict__ support_u,
        const unsigned int* __restrict__ rec4,
        const int* __restrict__ offsets,
        float* __restrict__ out, int n_nodes) {
    const int node = __builtin_amdgcn_readfirstlane(
        blockIdx.x * 4 + (threadIdx.x >> 6));
    const int lane = threadIdx.x & 63;
    if (node >= n_nodes) return;

    const int beg = offsets[node];
    const int end = offsets[node + 1];

    float ax = 0.f, ay = 0.f, bx = 0.f, by = 0.f;
    int e = beg;
    for (; e + 7 < end; e += 8) {
        unsigned r[8], s[8];
#pragma unroll
        for (int j = 0; j < 8; ++j) r[j] = rec4[e + j];
#pragma unroll
        for (int j = 0; j < 8; ++j)
            s[j] = support_u[(size_t)(r[j] >> 15) * 64 + lane];
#pragma unroll
        for (int j = 0; j < 8; ++j) {
            const float v = __half2float(__ushort_as_half((unsigned short)(r[j] & 0x7FFFu)));
            const float slo = __half2float(__ushort_as_half((unsigned short)(s[j] & 0xFFFFu)));
            const float shi = __half2float(__ushort_as_half((unsigned short)(s[j] >> 16)));
            if (j & 1) { bx += v * slo; by += v * shi; }
            else       { ax += v * slo; ay += v * shi; }
        }
    }
    for (; e + 3 < end; e += 4) {
        unsigned r[4], s[4];
#pragma unroll
        for (int j = 0; j < 4; ++j) r[j] = rec4[e + j];
#pragma unroll
        for (int j = 0; j < 4; ++j)
            s[j] = support_u[(size_t)(r[j] >> 15) * 64 + lane];
#pragma unroll
        for (int j = 0; j < 4; ++j) {
            const float v = __half2float(__ushort_as_half((unsigned short)(r[j] & 0x7FFFu)));
            const float slo = __half2float(__ushort_as_half((unsigned short)(s[j] & 0xFFFFu)));
            const float shi = __half2float(__ushort_as_half((unsigned short)(s[j] >> 16)));
            if (j & 1) { bx += v * slo; by += v * shi; }
            else       { ax += v * slo; ay += v * shi; }
        }
    }
    for (; e < end; ++e) {
        const unsigned r = rec4[e];
        const unsigned s = support_u[(size_t)(r >> 15) * 64 + lane];
        const float v = __half2float(__ushort_as_half((unsigned short)(r & 0x7FFFu)));
        ax += v * __half2float(__ushort_as_half((unsigned short)(s & 0xFFFFu)));
        ay += v * __half2float(__ushort_as_half((unsigned short)(s >> 16)));
    }

    floatx2 res;
    res.x = tanhf(ax + bx);
    res.y = tanhf(ay + by);
    floatx2* out2 = (floatx2*)out;
    __builtin_nontemporal_store(res, &out2[(size_t)node * 64 + lane]);
}

extern "C" void kernel_launch(void* const* d_in, const int* in_sizes, int n_in,
                              void* d_out, int out_size, void* d_ws, size_t ws_size,
                              hipStream_t stream) {
    const float* x    = (const float*)d_in[0];
    const float* W    = (const float*)d_in[1];
    const int*   erow = (const int*)d_in[2];
    const int*   ecol = (const int*)d_in[3];
    const float* eval = (const float*)d_in[4];
    float* out = (float*)d_out;

    const int n_nodes = in_sizes[0] / D;   // 100000
    const int n_edges = in_sizes[2];       // 1600000
    const int nbins = (n_nodes + BIN_ROWS - 1) >> BIN_SHIFT;      // 391

    // Workspace layout (16B alignment preserved per chunk)
    unsigned short* support2 = (unsigned short*)d_ws;             // 25.6 MB
    unsigned short* wt = support2 + (size_t)n_nodes * D;          // 32 KB
    uint2* tmp8   = (uint2*)(wt + D * D);                         // 12.8 MB
    unsigned int* rec4 = (unsigned int*)(tmp8 + n_edges);         // 6.4 MB
    int*  offsets = (int*)(rec4 + n_edges);                       // n_nodes+1
    int*  cbin    = offsets + n_nodes + 1;                        // NB_MAX
    int*  cbase   = cbin + NB_MAX;                                // NB_MAX+1
    int*  ccur    = cbase + NB_MAX + 1;                           // nbins*CPAD

    // cooperative grid size (cached): co-resident blocks only
    static int coopGrid = -1;
    if (coopGrid < 0) {
        int dev = 0;
        hipGetDevice(&dev);
        int numCU = 0, coop = 0, maxB = 0;
        hipDeviceGetAttribute(&numCU, hipDeviceAttributeMultiprocessorCount, dev);
        hipDeviceGetAttribute(&coop, hipDeviceAttributeCooperativeLaunch, dev);
        hipOccupancyMaxActiveBlocksPerMultiprocessor(&maxB, gcn_mega_kernel, 256, 0);
        coopGrid = (coop && numCU > 0 && maxB > 0) ? numCU * maxB : 0;
    }

    bool mega_ok = false;
    if (coopGrid > 0) {
        void* kargs[] = {
            (void*)&x, (void*)&W, (void*)&wt, (void*)&support2,
            (void*)&erow, (void*)&ecol, (void*)&eval,
            (void*)&cbin, (void*)&cbase, (void*)&ccur, (void*)&offsets,
            (void*)&tmp8, (void*)&rec4,
            (void*)&n_nodes, (void*)&n_edges, (void*)&nbins };
        mega_ok = (hipLaunchCooperativeKernel(
                       reinterpret_cast<void*>(gcn_mega_kernel),
                       dim3(coopGrid), dim3(256), kargs, 0, stream) == hipSuccess);
    }

    if (!mega_ok) {
        // fallback: proven round-5 style 6-launch pipeline
        gcn_wt_kernel<<<64, 256, 0, stream>>>(W, wt, cbin);
        gcn_gemm_kernel<<<(n_nodes + 127) / 128, 256, 0, stream>>>(
            x, wt, support2, n_nodes);
        gcn_chist_kernel<<<320, 256, 0, stream>>>(erow, cbin, n_edges);
        gcn_cscan_kernel<<<1, 256, 0, stream>>>(cbin, cbase, ccur, offsets,
                                                nbins, n_nodes, n_edges);
        gcn_binA_kernel<<<(n_edges + AW - 1) / AW, 256, 0, stream>>>(
            erow, ecol, eval, ccur, tmp8, n_edges, nbins);
        gcn_binB_kernel<<<nbins, 256, 0, stream>>>(tmp8, cbase, offsets, rec4,
                                                   n_nodes, nbins);
    }

    // per-node reduce + fused tanh (round-5 proven config)
    gcn_gather_kernel<<<(n_nodes + 3) / 4, 256, 0, stream>>>(
        (const unsigned int*)support2, rec4, offsets, out, n_nodes);
}

// Round 10
// 243.879 us; speedup vs baseline: 1.5435x; 1.5435x over previous
//
#include <hip/hip_runtime.h>
#include <hip/hip_bf16.h>
#include <hip/hip_fp16.h>
#include <math.h>

#define D 128
#define BIN_SHIFT 8      // 256 rows per coarse bin
#define BIN_ROWS 256
#define NB_MAX 512       // >= nbins (391 for 100k nodes)
#define CPAD 16          // ints; one 64B line per coarse cursor
#define AW 4096          // edges per stage-A block window
#define CHB 64           // partial-histogram blocks in prep

typedef _Float16 half8 __attribute__((ext_vector_type(8)));
typedef float floatx4 __attribute__((ext_vector_type(4)));
typedef float floatx2 __attribute__((ext_vector_type(2)));

// ---------------- L1 prep: wt transpose + ccur zero + partial chist --------
// 64 blocks x 256. Each block writes its OWN 512-slot histogram slice
// (no shared atomics -> no pre-zero ordering problem). Also zeroes the
// relative bin cursors and sets the CSR sentinel. Kernel boundary gives
// binA/binB a free grid barrier (stream order).
__global__ __launch_bounds__(256) void gcn_prep_kernel(
        const float* __restrict__ W, unsigned short* __restrict__ wt,
        int* __restrict__ ccur, int* __restrict__ part,
        int* __restrict__ offsets, const int* __restrict__ erow,
        int n_nodes, int n_edges) {
    __shared__ int h[NB_MAX];
    const int t = threadIdx.x;
    const int bid = blockIdx.x;
    const int gi = bid * 256 + t;          // 0..16383

    // wt[n*128+k] = f16(W[k*128+n])
    {
        const int n = gi >> 7, k = gi & 127;
        wt[gi] = __half_as_ushort(__float2half_rn(W[k * D + n]));
    }
    // zero relative cursors (NB_MAX*CPAD = 8192 ints)
    if (gi < NB_MAX * CPAD) ccur[gi] = 0;
    if (gi == 0) offsets[n_nodes] = n_edges;

    // partial coarse histogram
    h[t] = 0;
    h[t + 256] = 0;
    __syncthreads();
    const int nv = n_edges & ~3;
    const int stride = CHB * 256 * 4;
    for (int i = gi * 4; i + 3 < n_edges; i += stride) {
        const int4 r = *(const int4*)(erow + i);
        atomicAdd(&h[r.x >> BIN_SHIFT], 1);
        atomicAdd(&h[r.y >> BIN_SHIFT], 1);
        atomicAdd(&h[r.z >> BIN_SHIFT], 1);
        atomicAdd(&h[r.w >> BIN_SHIFT], 1);
    }
    if (bid == 0) {   // scalar tail (none for 1.6M, kept for safety)
        for (int i = nv + t; i < n_edges; i += 256)
            atomicAdd(&h[erow[i] >> BIN_SHIFT], 1);
    }
    __syncthreads();
    part[bid * NB_MAX + t] = h[t];
    part[bid * NB_MAX + t + 256] = h[t + 256];
}

// ---------------- GEMM: support_f16 = fp16(x @ W), f16 MFMA (r5 exact) -----
__global__ __launch_bounds__(256) void gcn_gemm_kernel(
        const float* __restrict__ x, const unsigned short* __restrict__ wt,
        unsigned short* __restrict__ support2, int n_nodes) {
    const int wave = threadIdx.x >> 6;
    const int lane = threadIdx.x & 63;
    const int q = lane >> 4;      // 0..3
    const int n16 = lane & 15;    // 0..15
    const int row_base = blockIdx.x * 128 + wave * 32;  // 32 rows per wave
    if (row_base >= n_nodes) return;   // 32 | 100000, no partial waves

    const half8* wt8 = (const half8*)wt;  // 16 B = 8 halves; wt row = 16 half8

    floatx4 acc[2][8];
#pragma unroll
    for (int mt = 0; mt < 2; ++mt)
#pragma unroll
        for (int nt = 0; nt < 8; ++nt) acc[mt][nt] = (floatx4){0.f, 0.f, 0.f, 0.f};

#pragma unroll
    for (int kc = 0; kc < 4; ++kc) {
        half8 b[8];
#pragma unroll
        for (int nt = 0; nt < 8; ++nt)
            b[nt] = wt8[(nt * 16 + n16) * 16 + kc * 4 + q];
#pragma unroll
        for (int mt = 0; mt < 2; ++mt) {
            const float* xp = x + (size_t)(row_base + mt * 16 + n16) * D
                                + kc * 32 + q * 8;
            const float4 f0 = *(const float4*)xp;
            const float4 f1 = *(const float4*)(xp + 4);
            half8 a;
            a[0] = (_Float16)f0.x; a[1] = (_Float16)f0.y;
            a[2] = (_Float16)f0.z; a[3] = (_Float16)f0.w;
            a[4] = (_Float16)f1.x; a[5] = (_Float16)f1.y;
            a[6] = (_Float16)f1.z; a[7] = (_Float16)f1.w;
#pragma unroll
            for (int nt = 0; nt < 8; ++nt)
                acc[mt][nt] = __builtin_amdgcn_mfma_f32_16x16x32_f16(
                    a, b[nt], acc[mt][nt], 0, 0, 0);
        }
    }

#pragma unroll
    for (int mt = 0; mt < 2; ++mt) {
        const int r0 = row_base + mt * 16 + q * 4;
#pragma unroll
        for (int nt = 0; nt < 8; ++nt) {
            const int col = nt * 16 + n16;
#pragma unroll
            for (int i = 0; i < 4; ++i)
                support2[(size_t)(r0 + i) * D + col] =
                    __half_as_ushort(__float2half_rn(acc[mt][nt][i]));
        }
    }
}

// ---------------- Stage A: counting sort into coarse bins (r5 + local cbase)
// New prologue: sum 64 partials per bin (coalesced) + 512-wide scan -> cbs[].
// Global cursors are RELATIVE (zeroed in prep): gbase = cbs[b] + rel.
__global__ __launch_bounds__(512) void gcn_binA_kernel(
        const int* __restrict__ erow, const int* __restrict__ ecol,
        const float* __restrict__ eval, const int* __restrict__ part,
        int* __restrict__ ccur, uint2* __restrict__ tmp8,
        int n_edges, int nbins) {
    __shared__ uint2 recs[AW];      // 32 KB
    __shared__ int cbs[NB_MAX];     // global exclusive bin bases
    __shared__ int hist[NB_MAX];
    __shared__ int lstart[NB_MAX];
    __shared__ int gbase[NB_MAX];
    const int t = threadIdx.x;
    const int w0 = blockIdx.x * AW;
    const int wend = min(w0 + AW, n_edges);
    const int cnt = wend - w0;

    // local cbase: sum partials (1 bin/thread, coalesced) + scan
    int csum = 0;
#pragma unroll 8
    for (int k = 0; k < CHB; ++k) csum += part[k * NB_MAX + t];
    hist[t] = csum;
    __syncthreads();
    for (int off = 1; off < 512; off <<= 1) {
        int tv = (t >= off) ? hist[t - off] : 0;
        __syncthreads();
        hist[t] += tv;
        __syncthreads();
    }
    cbs[t] = hist[t] - csum;
    __syncthreads();
    hist[t] = 0;
    __syncthreads();

    // window histogram
    for (int i = w0 + t; i < wend; i += 512)
        atomicAdd(&hist[erow[i] >> BIN_SHIFT], 1);
    __syncthreads();

    // scan for window-local starts
    {
        const int v = hist[t];
        gbase[t] = v;
        __syncthreads();
        for (int off = 1; off < 512; off <<= 1) {
            int tv = (t >= off) ? gbase[t - off] : 0;
            __syncthreads();
            gbase[t] += tv;
            __syncthreads();
        }
        lstart[t] = gbase[t] - v;
        __syncthreads();
    }

    // reserve contiguous global ranges: relative bump + local base
    {
        const int c = hist[t];
        int gb = 0;
        if (t < nbins && c > 0) gb = cbs[t] + atomicAdd(&ccur[t * CPAD], c);
        __syncthreads();
        gbase[t] = gb;
        hist[t] = lstart[t];
    }
    __syncthreads();

    // local placement into LDS
    for (int i = w0 + t; i < wend; i += 512) {
        const int r = erow[i];
        const int c = ecol[i];
        const unsigned short vh = __half_as_ushort(__float2half_rn(eval[i]));
        const int b = r >> BIN_SHIFT;
        const int p = atomicAdd(&hist[b], 1);
        recs[p] = make_uint2(((unsigned)r << 15) | vh, (unsigned)c);
    }
    __syncthreads();

    // ordered (coalesced-run) write-out
    for (int s = t; s < cnt; s += 512) {
        const uint2 rec = recs[s];
        const int b = (int)(rec.x >> 15) >> BIN_SHIFT;
        tmp8[gbase[b] + (s - lstart[b])] = rec;
    }
}

// ---------------- Stage B: per-row offsets + CSR placement (r5 + local beg) -
__global__ __launch_bounds__(256) void gcn_binB_kernel(
        const uint2* __restrict__ tmp8, const int* __restrict__ part,
        int* __restrict__ offsets, unsigned int* __restrict__ rec4,
        int n_nodes, int nbins) {
    __shared__ int cnt[BIN_ROWS];
    __shared__ int sm[256];
    __shared__ int bb[2];           // beg, end of this bin
    const int bin = blockIdx.x;
    const int r0 = bin << BIN_SHIFT;
    const int t = threadIdx.x;

    // local cbase for bins 2t, 2t+1: sum partials (int2, coalesced) + scan
    int s0 = 0, s1 = 0;
    const int2* p2 = (const int2*)part;   // part row = 256 int2
#pragma unroll 8
    for (int k = 0; k < CHB; ++k) {
        const int2 p = p2[k * 256 + t];
        s0 += p.x; s1 += p.y;
    }
    const int s2 = s0 + s1;
    sm[t] = s2;
    __syncthreads();
    for (int off = 1; off < 256; off <<= 1) {
        int tv = (t >= off) ? sm[t - off] : 0;
        __syncthreads();
        sm[t] += tv;
        __syncthreads();
    }
    const int ex = sm[t] - s2;            // exclusive prefix before bin 2t
    if (2 * t == bin)     bb[0] = ex;
    if (2 * t + 1 == bin) bb[0] = ex + s0;
    if (2 * t == bin + 1)     bb[1] = ex;
    if (2 * t + 1 == bin + 1) bb[1] = ex + s0;
    if (t == 255 && bin + 1 == NB_MAX) bb[1] = sm[255];  // safety
    __syncthreads();
    const int beg = bb[0];
    const int end = bb[1];

    cnt[t] = 0;
    __syncthreads();

    // pass 1: per-row histogram within the bin
    for (int i = beg + t; i < end; i += 256)
        atomicAdd(&cnt[(int)(tmp8[i].x >> 15) - r0], 1);
    __syncthreads();

    // exclusive scan over 256 counters (1 per thread)
    const int v = cnt[t];
    sm[t] = v;
    __syncthreads();
    for (int off = 1; off < 256; off <<= 1) {
        int tv = (t >= off) ? sm[t - off] : 0;
        __syncthreads();
        sm[t] += tv;
        __syncthreads();
    }
    const int mypos = beg + sm[t] - v;   // global CSR start for row r0+t

    const int row = r0 + t;
    if (row < n_nodes) offsets[row] = mypos;
    __syncthreads();
    cnt[t] = mypos;                      // per-row cursor
    __syncthreads();

    // pass 2: placement (tmp8 slice L2-hot from pass 1)
    for (int i = beg + t; i < end; i += 256) {
        const uint2 p = tmp8[i];
        const int pos = atomicAdd(&cnt[(int)(p.x >> 15) - r0], 1);
        rec4[pos] = (p.y << 15) | (p.x & 0x7FFFu);
    }
}

// ---------------- per-node reduction + fused tanh (round-5 proven) ---------
__global__ __launch_bounds__(256) void gcn_gather_kernel(
        const unsigned int* __restrict__ support_u,
        const unsigned int* __restrict__ rec4,
        const int* __restrict__ offsets,
        float* __restrict__ out, int n_nodes) {
    const int node = __builtin_amdgcn_readfirstlane(
        blockIdx.x * 4 + (threadIdx.x >> 6));
    const int lane = threadIdx.x & 63;
    if (node >= n_nodes) return;

    const int beg = offsets[node];
    const int end = offsets[node + 1];

    float ax = 0.f, ay = 0.f, bx = 0.f, by = 0.f;
    int e = beg;
    for (; e + 7 < end; e += 8) {
        unsigned r[8], s[8];
#pragma unroll
        for (int j = 0; j < 8; ++j) r[j] = rec4[e + j];
#pragma unroll
        for (int j = 0; j < 8; ++j)
            s[j] = support_u[(size_t)(r[j] >> 15) * 64 + lane];
#pragma unroll
        for (int j = 0; j < 8; ++j) {
            const float v = __half2float(__ushort_as_half((unsigned short)(r[j] & 0x7FFFu)));
            const float slo = __half2float(__ushort_as_half((unsigned short)(s[j] & 0xFFFFu)));
            const float shi = __half2float(__ushort_as_half((unsigned short)(s[j] >> 16)));
            if (j & 1) { bx += v * slo; by += v * shi; }
            else       { ax += v * slo; ay += v * shi; }
        }
    }
    for (; e + 3 < end; e += 4) {
        unsigned r[4], s[4];
#pragma unroll
        for (int j = 0; j < 4; ++j) r[j] = rec4[e + j];
#pragma unroll
        for (int j = 0; j < 4; ++j)
            s[j] = support_u[(size_t)(r[j] >> 15) * 64 + lane];
#pragma unroll
        for (int j = 0; j < 4; ++j) {
            const float v = __half2float(__ushort_as_half((unsigned short)(r[j] & 0x7FFFu)));
            const float slo = __half2float(__ushort_as_half((unsigned short)(s[j] & 0xFFFFu)));
            const float shi = __half2float(__ushort_as_half((unsigned short)(s[j] >> 16)));
            if (j & 1) { bx += v * slo; by += v * shi; }
            else       { ax += v * slo; ay += v * shi; }
        }
    }
    for (; e < end; ++e) {
        const unsigned r = rec4[e];
        const unsigned s = support_u[(size_t)(r >> 15) * 64 + lane];
        const float v = __half2float(__ushort_as_half((unsigned short)(r & 0x7FFFu)));
        ax += v * __half2float(__ushort_as_half((unsigned short)(s & 0xFFFFu)));
        ay += v * __half2float(__ushort_as_half((unsigned short)(s >> 16)));
    }

    floatx2 res;
    res.x = tanhf(ax + bx);
    res.y = tanhf(ay + by);
    floatx2* out2 = (floatx2*)out;
    // non-temporal: keep the 50MB out stream from evicting support in L2
    __builtin_nontemporal_store(res, &out2[(size_t)node * 64 + lane]);
}

extern "C" void kernel_launch(void* const* d_in, const int* in_sizes, int n_in,
                              void* d_out, int out_size, void* d_ws, size_t ws_size,
                              hipStream_t stream) {
    const float* x    = (const float*)d_in[0];
    const float* W    = (const float*)d_in[1];
    const int*   erow = (const int*)d_in[2];
    const int*   ecol = (const int*)d_in[3];
    const float* eval = (const float*)d_in[4];
    float* out = (float*)d_out;

    const int n_nodes = in_sizes[0] / D;   // 100000
    const int n_edges = in_sizes[2];       // 1600000
    const int nbins = (n_nodes + BIN_ROWS - 1) >> BIN_SHIFT;      // 391

    // Workspace layout (16B alignment preserved per chunk)
    unsigned short* support2 = (unsigned short*)d_ws;             // 25.6 MB
    unsigned short* wt = support2 + (size_t)n_nodes * D;          // 32 KB
    uint2* tmp8   = (uint2*)(wt + D * D);                         // 12.8 MB
    unsigned int* rec4 = (unsigned int*)(tmp8 + n_edges);         // 6.4 MB
    int*  offsets = (int*)(rec4 + n_edges);                       // n_nodes+1
    int*  part    = offsets + n_nodes + 1;                        // CHB*NB_MAX (128 KB)
    int*  ccur    = part + CHB * NB_MAX;                          // NB_MAX*CPAD

    // L1: wt transpose + ccur zero + partial coarse histogram + sentinel
    gcn_prep_kernel<<<CHB, 256, 0, stream>>>(W, wt, ccur, part, offsets,
                                             erow, n_nodes, n_edges);
    // L2: GEMM (also acts as grid barrier for prep outputs)
    gcn_gemm_kernel<<<(n_nodes + 127) / 128, 256, 0, stream>>>(
        x, wt, support2, n_nodes);
    // L3: stage-A binning (local cbase from partials)
    gcn_binA_kernel<<<(n_edges + AW - 1) / AW, 512, 0, stream>>>(
        erow, ecol, eval, part, ccur, tmp8, n_edges, nbins);
    // L4: stage-B CSR build (local beg/end from partials)
    gcn_binB_kernel<<<nbins, 256, 0, stream>>>(tmp8, part, offsets, rec4,
                                               n_nodes, nbins);
    // L5: per-node reduce + fused tanh
    gcn_gather_kernel<<<(n_nodes + 3) / 4, 256, 0, stream>>>(
        (const unsigned int*)support2, rec4, offsets, out, n_nodes);
}

// Round 11
// 241.315 us; speedup vs baseline: 1.5599x; 1.0106x over previous
//
#include <hip/hip_runtime.h>
#include <hip/hip_bf16.h>
#include <hip/hip_fp16.h>
#include <math.h>

#define D 128
#define BIN_SHIFT 8      // 256 rows per coarse bin
#define BIN_ROWS 256
#define NB_MAX 512       // >= nbins (391 for 100k nodes)
#define CPAD 16          // ints; one 64B line per coarse cursor
#define AW 4096          // edges per stage-A block window
#define CHB 64           // partial-histogram blocks in prep
#define GT 256           // gemm rows per fused block (512 thr x 32 rows/wave)

typedef _Float16 half8 __attribute__((ext_vector_type(8)));
typedef float floatx4 __attribute__((ext_vector_type(4)));
typedef float floatx2 __attribute__((ext_vector_type(2)));

// ---------------- L1 prep: wt transpose + ccur zero + partial chist --------
__global__ __launch_bounds__(256) void gcn_prep_kernel(
        const float* __restrict__ W, unsigned short* __restrict__ wt,
        int* __restrict__ ccur, int* __restrict__ part,
        int* __restrict__ offsets, const int* __restrict__ erow,
        int n_nodes, int n_edges) {
    __shared__ int h[NB_MAX];
    const int t = threadIdx.x;
    const int bid = blockIdx.x;
    const int gi = bid * 256 + t;          // 0..16383

    {   // wt[n*128+k] = f16(W[k*128+n])
        const int n = gi >> 7, k = gi & 127;
        wt[gi] = __half_as_ushort(__float2half_rn(W[k * D + n]));
    }
    if (gi < NB_MAX * CPAD) ccur[gi] = 0;
    if (gi == 0) offsets[n_nodes] = n_edges;

    h[t] = 0;
    h[t + 256] = 0;
    __syncthreads();
    const int nv = n_edges & ~3;
    const int stride = CHB * 256 * 4;
    for (int i = gi * 4; i + 3 < n_edges; i += stride) {
        const int4 r = *(const int4*)(erow + i);
        atomicAdd(&h[r.x >> BIN_SHIFT], 1);
        atomicAdd(&h[r.y >> BIN_SHIFT], 1);
        atomicAdd(&h[r.z >> BIN_SHIFT], 1);
        atomicAdd(&h[r.w >> BIN_SHIFT], 1);
    }
    if (bid == 0) {   // scalar tail (none for 1.6M, kept for safety)
        for (int i = nv + t; i < n_edges; i += 256)
            atomicAdd(&h[erow[i] >> BIN_SHIFT], 1);
    }
    __syncthreads();
    part[bid * NB_MAX + t] = h[t];
    part[bid * NB_MAX + t + 256] = h[t + 256];
}

// ---------------- gemm tile body (512 thr, 256 rows/tile) ------------------
__device__ __forceinline__ void gemm_tile(
        const float* __restrict__ x, const unsigned short* __restrict__ wt,
        unsigned short* __restrict__ support2, int n_nodes, int tile) {
    const int wave = threadIdx.x >> 6;    // 0..7
    const int lane = threadIdx.x & 63;
    const int q = lane >> 4;
    const int n16 = lane & 15;
    const int row_base = tile * GT + wave * 32;
    if (row_base >= n_nodes) return;   // 32 | 100000; no partial waves

    const half8* wt8 = (const half8*)wt;

    floatx4 acc[2][8];
#pragma unroll
    for (int mt = 0; mt < 2; ++mt)
#pragma unroll
        for (int nt = 0; nt < 8; ++nt) acc[mt][nt] = (floatx4){0.f, 0.f, 0.f, 0.f};

#pragma unroll
    for (int kc = 0; kc < 4; ++kc) {
        half8 b[8];
#pragma unroll
        for (int nt = 0; nt < 8; ++nt)
            b[nt] = wt8[(nt * 16 + n16) * 16 + kc * 4 + q];
#pragma unroll
        for (int mt = 0; mt < 2; ++mt) {
            const float* xp = x + (size_t)(row_base + mt * 16 + n16) * D
                                + kc * 32 + q * 8;
            const float4 f0 = *(const float4*)xp;
            const float4 f1 = *(const float4*)(xp + 4);
            half8 a;
            a[0] = (_Float16)f0.x; a[1] = (_Float16)f0.y;
            a[2] = (_Float16)f0.z; a[3] = (_Float16)f0.w;
            a[4] = (_Float16)f1.x; a[5] = (_Float16)f1.y;
            a[6] = (_Float16)f1.z; a[7] = (_Float16)f1.w;
#pragma unroll
            for (int nt = 0; nt < 8; ++nt)
                acc[mt][nt] = __builtin_amdgcn_mfma_f32_16x16x32_f16(
                    a, b[nt], acc[mt][nt], 0, 0, 0);
        }
    }

#pragma unroll
    for (int mt = 0; mt < 2; ++mt) {
        const int r0 = row_base + mt * 16 + q * 4;
#pragma unroll
        for (int nt = 0; nt < 8; ++nt) {
            const int col = nt * 16 + n16;
#pragma unroll
            for (int i = 0; i < 4; ++i)
                support2[(size_t)(r0 + i) * D + col] =
                    __half_as_ushort(__float2half_rn(acc[mt][nt][i]));
        }
    }
}

// ---------------- fused GEMM | binA kernel ---------------------------------
// Even blocks: one binA window (staged counting sort, r10-proven, local
// cbase from partials). Odd blocks: one 256-row GEMM tile. Independent
// roles; block interleave keeps MFMA and memory pipes co-resident so the
// two phases overlap instead of serializing across launches.
__global__ __launch_bounds__(512) void gcn_gemmbinA_kernel(
        const float* __restrict__ x, const unsigned short* __restrict__ wt,
        unsigned short* __restrict__ support2,
        const int* __restrict__ erow, const int* __restrict__ ecol,
        const float* __restrict__ eval, const int* __restrict__ part,
        int* __restrict__ ccur, uint2* __restrict__ tmp8,
        int n_nodes, int n_edges, int nbins, int nwa) {
    __shared__ uint2 recs[AW];      // 32 KB (binA path only)
    __shared__ int cbs[NB_MAX];
    __shared__ int hist[NB_MAX];
    __shared__ int lstart[NB_MAX];
    __shared__ int gbase[NB_MAX];
    const int bid = blockIdx.x;

    // interleave roles: even = binA window, odd = gemm tile (nwa == ngt here;
    // guard handles any mismatch)
    const int pair = bid >> 1;
    if ((bid & 1) && pair * GT < n_nodes) {
        gemm_tile(x, wt, support2, n_nodes, pair);
        return;
    }
    const int w = (bid & 1) ? -1 : pair;
    if (w < 0 || w >= nwa) return;

    const int t = threadIdx.x;
    const int w0 = w * AW;
    const int wend = min(w0 + AW, n_edges);
    const int cnt = wend - w0;

    // local cbase: sum partials (1 bin/thread, coalesced) + scan
    int csum = 0;
#pragma unroll 8
    for (int k = 0; k < CHB; ++k) csum += part[k * NB_MAX + t];
    hist[t] = csum;
    __syncthreads();
    for (int off = 1; off < 512; off <<= 1) {
        int tv = (t >= off) ? hist[t - off] : 0;
        __syncthreads();
        hist[t] += tv;
        __syncthreads();
    }
    cbs[t] = hist[t] - csum;
    __syncthreads();
    hist[t] = 0;
    __syncthreads();

    // window histogram
    for (int i = w0 + t; i < wend; i += 512)
        atomicAdd(&hist[erow[i] >> BIN_SHIFT], 1);
    __syncthreads();

    // scan for window-local starts
    {
        const int v = hist[t];
        gbase[t] = v;
        __syncthreads();
        for (int off = 1; off < 512; off <<= 1) {
            int tv = (t >= off) ? gbase[t - off] : 0;
            __syncthreads();
            gbase[t] += tv;
            __syncthreads();
        }
        lstart[t] = gbase[t] - v;
        __syncthreads();
    }

    // reserve contiguous global ranges: relative bump + local base
    {
        const int c = hist[t];
        int gb = 0;
        if (t < nbins && c > 0) gb = cbs[t] + atomicAdd(&ccur[t * CPAD], c);
        __syncthreads();
        gbase[t] = gb;
        hist[t] = lstart[t];
    }
    __syncthreads();

    // local placement into LDS
    for (int i = w0 + t; i < wend; i += 512) {
        const int r = erow[i];
        const int c = ecol[i];
        const unsigned short vh = __half_as_ushort(__float2half_rn(eval[i]));
        const int b = r >> BIN_SHIFT;
        const int p = atomicAdd(&hist[b], 1);
        recs[p] = make_uint2(((unsigned)r << 15) | vh, (unsigned)c);
    }
    __syncthreads();

    // ordered (coalesced-run) write-out
    for (int s = t; s < cnt; s += 512) {
        const uint2 rec = recs[s];
        const int b = (int)(rec.x >> 15) >> BIN_SHIFT;
        tmp8[gbase[b] + (s - lstart[b])] = rec;
    }
}

// ---------------- Stage B: per-row offsets + CSR placement (r10 exact) -----
__global__ __launch_bounds__(256) void gcn_binB_kernel(
        const uint2* __restrict__ tmp8, const int* __restrict__ part,
        int* __restrict__ offsets, unsigned int* __restrict__ rec4,
        int n_nodes, int nbins) {
    __shared__ int cnt[BIN_ROWS];
    __shared__ int sm[256];
    __shared__ int bb[2];           // beg, end of this bin
    const int bin = blockIdx.x;
    const int r0 = bin << BIN_SHIFT;
    const int t = threadIdx.x;

    // local cbase for bins 2t, 2t+1: sum partials (int2, coalesced) + scan
    int s0 = 0, s1 = 0;
    const int2* p2 = (const int2*)part;   // part row = 256 int2
#pragma unroll 8
    for (int k = 0; k < CHB; ++k) {
        const int2 p = p2[k * 256 + t];
        s0 += p.x; s1 += p.y;
    }
    const int s2 = s0 + s1;
    sm[t] = s2;
    __syncthreads();
    for (int off = 1; off < 256; off <<= 1) {
        int tv = (t >= off) ? sm[t - off] : 0;
        __syncthreads();
        sm[t] += tv;
        __syncthreads();
    }
    const int ex = sm[t] - s2;            // exclusive prefix before bin 2t
    if (2 * t == bin)     bb[0] = ex;
    if (2 * t + 1 == bin) bb[0] = ex + s0;
    if (2 * t == bin + 1)     bb[1] = ex;
    if (2 * t + 1 == bin + 1) bb[1] = ex + s0;
    if (t == 255 && bin + 1 == NB_MAX) bb[1] = sm[255];  // safety
    __syncthreads();
    const int beg = bb[0];
    const int end = bb[1];

    cnt[t] = 0;
    __syncthreads();

    // pass 1: per-row histogram within the bin
    for (int i = beg + t; i < end; i += 256)
        atomicAdd(&cnt[(int)(tmp8[i].x >> 15) - r0], 1);
    __syncthreads();

    // exclusive scan over 256 counters (1 per thread)
    const int v = cnt[t];
    sm[t] = v;
    __syncthreads();
    for (int off = 1; off < 256; off <<= 1) {
        int tv = (t >= off) ? sm[t - off] : 0;
        __syncthreads();
        sm[t] += tv;
        __syncthreads();
    }
    const int mypos = beg + sm[t] - v;   // global CSR start for row r0+t

    const int row = r0 + t;
    if (row < n_nodes) offsets[row] = mypos;
    __syncthreads();
    cnt[t] = mypos;                      // per-row cursor
    __syncthreads();

    // pass 2: placement (tmp8 slice L2-hot from pass 1)
    for (int i = beg + t; i < end; i += 256) {
        const uint2 p = tmp8[i];
        const int pos = atomicAdd(&cnt[(int)(p.x >> 15) - r0], 1);
        rec4[pos] = (p.y << 15) | (p.x & 0x7FFFu);
    }
}

// ---------------- per-node reduction + fused tanh (round-5 proven) ---------
__global__ __launch_bounds__(256) void gcn_gather_kernel(
        const unsigned int* __restrict__ support_u,
        const unsigned int* __restrict__ rec4,
        const int* __restrict__ offsets,
        float* __restrict__ out, int n_nodes) {
    const int node = __builtin_amdgcn_readfirstlane(
        blockIdx.x * 4 + (threadIdx.x >> 6));
    const int lane = threadIdx.x & 63;
    if (node >= n_nodes) return;

    const int beg = offsets[node];
    const int end = offsets[node + 1];

    float ax = 0.f, ay = 0.f, bx = 0.f, by = 0.f;
    int e = beg;
    for (; e + 7 < end; e += 8) {
        unsigned r[8], s[8];
#pragma unroll
        for (int j = 0; j < 8; ++j) r[j] = rec4[e + j];
#pragma unroll
        for (int j = 0; j < 8; ++j)
            s[j] = support_u[(size_t)(r[j] >> 15) * 64 + lane];
#pragma unroll
        for (int j = 0; j < 8; ++j) {
            const float v = __half2float(__ushort_as_half((unsigned short)(r[j] & 0x7FFFu)));
            const float slo = __half2float(__ushort_as_half((unsigned short)(s[j] & 0xFFFFu)));
            const float shi = __half2float(__ushort_as_half((unsigned short)(s[j] >> 16)));
            if (j & 1) { bx += v * slo; by += v * shi; }
            else       { ax += v * slo; ay += v * shi; }
        }
    }
    for (; e + 3 < end; e += 4) {
        unsigned r[4], s[4];
#pragma unroll
        for (int j = 0; j < 4; ++j) r[j] = rec4[e + j];
#pragma unroll
        for (int j = 0; j < 4; ++j)
            s[j] = support_u[(size_t)(r[j] >> 15) * 64 + lane];
#pragma unroll
        for (int j = 0; j < 4; ++j) {
            const float v = __half2float(__ushort_as_half((unsigned short)(r[j] & 0x7FFFu)));
            const float slo = __half2float(__ushort_as_half((unsigned short)(s[j] & 0xFFFFu)));
            const float shi = __half2float(__ushort_as_half((unsigned short)(s[j] >> 16)));
            if (j & 1) { bx += v * slo; by += v * shi; }
            else       { ax += v * slo; ay += v * shi; }
        }
    }
    for (; e < end; ++e) {
        const unsigned r = rec4[e];
        const unsigned s = support_u[(size_t)(r >> 15) * 64 + lane];
        const float v = __half2float(__ushort_as_half((unsigned short)(r & 0x7FFFu)));
        ax += v * __half2float(__ushort_as_half((unsigned short)(s & 0xFFFFu)));
        ay += v * __half2float(__ushort_as_half((unsigned short)(s >> 16)));
    }

    floatx2 res;
    res.x = tanhf(ax + bx);
    res.y = tanhf(ay + by);
    floatx2* out2 = (floatx2*)out;
    __builtin_nontemporal_store(res, &out2[(size_t)node * 64 + lane]);
}

extern "C" void kernel_launch(void* const* d_in, const int* in_sizes, int n_in,
                              void* d_out, int out_size, void* d_ws, size_t ws_size,
                              hipStream_t stream) {
    const float* x    = (const float*)d_in[0];
    const float* W    = (const float*)d_in[1];
    const int*   erow = (const int*)d_in[2];
    const int*   ecol = (const int*)d_in[3];
    const float* eval = (const float*)d_in[4];
    float* out = (float*)d_out;

    const int n_nodes = in_sizes[0] / D;   // 100000
    const int n_edges = in_sizes[2];       // 1600000
    const int nbins = (n_nodes + BIN_ROWS - 1) >> BIN_SHIFT;      // 391
    const int nwa = (n_edges + AW - 1) / AW;                      // 391
    const int ngt = (n_nodes + GT - 1) / GT;                      // 391

    // Workspace layout (16B alignment preserved per chunk)
    unsigned short* support2 = (unsigned short*)d_ws;             // 25.6 MB
    unsigned short* wt = support2 + (size_t)n_nodes * D;          // 32 KB
    uint2* tmp8   = (uint2*)(wt + D * D);                         // 12.8 MB
    unsigned int* rec4 = (unsigned int*)(tmp8 + n_edges);         // 6.4 MB
    int*  offsets = (int*)(rec4 + n_edges);                       // n_nodes+1
    int*  part    = offsets + n_nodes + 1;                        // CHB*NB_MAX (128 KB)
    int*  ccur    = part + CHB * NB_MAX;                          // NB_MAX*CPAD

    // L1: wt transpose + ccur zero + partial coarse histogram + sentinel
    gcn_prep_kernel<<<CHB, 256, 0, stream>>>(W, wt, ccur, part, offsets,
                                             erow, n_nodes, n_edges);
    // L2: fused GEMM | binA (independent roles, block-interleaved)
    gcn_gemmbinA_kernel<<<nwa + ngt, 512, 0, stream>>>(
        x, wt, support2, erow, ecol, eval, part, ccur, tmp8,
        n_nodes, n_edges, nbins, nwa);
    // L3: stage-B CSR build (local beg/end from partials)
    gcn_binB_kernel<<<nbins, 256, 0, stream>>>(tmp8, part, offsets, rec4,
                                               n_nodes, nbins);
    // L4: per-node reduce + fused tanh
    gcn_gather_kernel<<<(n_nodes + 3) / 4, 256, 0, stream>>>(
        (const unsigned int*)support2, rec4, offsets, out, n_nodes);
}